// Round 10
// baseline (502.474 us; speedup 1.0000x reference)
//
#include <hip/hip_runtime.h>
#include <hip/hip_bf16.h>

#define N_NODES 50000
#define E_EDGES 800000
#define ET (E_EDGES + N_NODES)
#define G_GRAPHS 64
#define IN_F 128
#define HID 64
#define HEADS 4
#define HC (HID * HEADS)
#define NC 2
#define SLOPE 0.2f
#define L2E 1.4426950408889634f

typedef float f32x4 __attribute__((ext_vector_type(4)));
typedef __bf16 bf16x8 __attribute__((ext_vector_type(8)));
typedef unsigned short us8 __attribute__((ext_vector_type(8)));
typedef unsigned short us4 __attribute__((ext_vector_type(4)));
typedef _Float16 h16x4 __attribute__((ext_vector_type(4)));

#define MFMA16(a, b, c) \
  __builtin_amdgcn_mfma_f32_16x16x32_bf16(__builtin_bit_cast(bf16x8, (a)), \
                                          __builtin_bit_cast(bf16x8, (b)), (c), 0, 0, 0)

__device__ inline unsigned short f2bf_rne(float f) {
  unsigned u = __builtin_bit_cast(unsigned, f);
  u += 0x7fffu + ((u >> 16) & 1u);
  return (unsigned short)(u >> 16);
}
__device__ inline float bf2f(unsigned short h) {
  unsigned u = ((unsigned)h) << 16;
  return __builtin_bit_cast(float, u);
}

// ---------------- fused split/cast kernel ----------------

__device__ inline void split4(const float* __restrict__ in, unsigned short* __restrict__ hi,
                              unsigned short* __restrict__ lo, int i) {
  float4 v = *(const float4*)&in[i];
  float f[4] = {v.x, v.y, v.z, v.w};
  us4 h, l;
#pragma unroll
  for (int j = 0; j < 4; j++) {
    unsigned short hb = f2bf_rne(f[j]);
    h[j] = hb;
    l[j] = f2bf_rne(f[j] - bf2f(hb));
  }
  *(us4*)&hi[i] = h;
  *(us4*)&lo[i] = l;
}

#define QX (N_NODES * IN_F / 4)
#define QW1 (HC * IN_F / 4)
#define QW2 (HC * HC / 4)
#define QTOT (QX + QW1 + 2 * QW2)

__global__ __launch_bounds__(256) void split_all_kernel(
    const float* __restrict__ x, const float* __restrict__ W1,
    const float* __restrict__ W2, const float* __restrict__ W3,
    unsigned short* __restrict__ xhi,
    unsigned short* __restrict__ w1h, unsigned short* __restrict__ w1l,
    unsigned short* __restrict__ w2h, unsigned short* __restrict__ w2l,
    unsigned short* __restrict__ w3h, unsigned short* __restrict__ w3l) {
  int q = blockIdx.x * 256 + threadIdx.x;
  if (q < QX) {
    int i = q * 4;
    float4 v = *(const float4*)&x[i];
    float f[4] = {v.x, v.y, v.z, v.w};
    us4 h;
#pragma unroll
    for (int j = 0; j < 4; j++) h[j] = f2bf_rne(f[j]);
    *(us4*)&xhi[i] = h;
  } else if (q < QX + QW1) {
    split4(W1, w1h, w1l, (q - QX) * 4);
  } else if (q < QX + QW1 + QW2) {
    split4(W2, w2h, w2l, (q - QX - QW1) * 4);
  } else {
    split4(W3, w3h, w3l, (q - QX - QW1 - QW2) * 4);
  }
}

// ---------------- CSR build ----------------

__global__ void count_kernel(const int* __restrict__ ei, int* __restrict__ cnt) {
  int e = blockIdx.x * blockDim.x + threadIdx.x;
  if (e >= ET) return;
  int dst = (e < E_EDGES) ? ei[E_EDGES + e] : (e - E_EDGES);
  atomicAdd(&cnt[dst], 1);
}

#define SCAN_BLOCKS ((N_NODES + 255) / 256)

__global__ __launch_bounds__(256) void scan1_kernel(const int* __restrict__ cnt,
                                                    int* __restrict__ incl_buf,
                                                    int* __restrict__ partial) {
  __shared__ int ws[4];
  int tid = threadIdx.x, b = blockIdx.x;
  int wave = tid >> 6, lane = tid & 63;
  int i = b * 256 + tid;
  int v = (i < N_NODES) ? cnt[i] : 0;
  int x = v;
#pragma unroll
  for (int off = 1; off < 64; off <<= 1) {
    int t = __shfl_up(x, off, 64);
    if (lane >= off) x += t;
  }
  if (lane == 63) ws[wave] = x;
  __syncthreads();
  if (tid == 0) {
    int s = 0;
#pragma unroll
    for (int w = 0; w < 4; w++) { int t = ws[w]; ws[w] = s; s += t; }
    partial[b] = s;
  }
  __syncthreads();
  if (i < N_NODES) incl_buf[i] = x + ws[wave];
}

__global__ __launch_bounds__(256) void scan2_kernel(int* __restrict__ partial) {
  __shared__ int ws[4];
  int tid = threadIdx.x;
  int wave = tid >> 6, lane = tid & 63;
  int v = (tid < SCAN_BLOCKS) ? partial[tid] : 0;
  int x = v;
#pragma unroll
  for (int off = 1; off < 64; off <<= 1) {
    int t = __shfl_up(x, off, 64);
    if (lane >= off) x += t;
  }
  if (lane == 63) ws[wave] = x;
  __syncthreads();
  if (tid == 0) {
    int s = 0;
#pragma unroll
    for (int w = 0; w < 4; w++) { int t = ws[w]; ws[w] = s; s += t; }
  }
  __syncthreads();
  partial[tid] = x + ws[wave] - v;
}

__global__ __launch_bounds__(256) void scan3_kernel(const int* __restrict__ cnt,
                                                    int* __restrict__ incl_buf,
                                                    const int* __restrict__ partial,
                                                    int* __restrict__ rowptr,
                                                    int* __restrict__ cursor) {
  int tid = threadIdx.x, b = blockIdx.x;
  int i = b * 256 + tid;
  if (i >= N_NODES) return;
  int incl = incl_buf[i] + partial[b];
  rowptr[i + 1] = incl;
  cursor[i] = incl - cnt[i];
  if (i == 0) rowptr[0] = 0;
}

__global__ void scatter_kernel(const int* __restrict__ ei, int* __restrict__ cursor,
                               int* __restrict__ csr_src) {
  int e = blockIdx.x * blockDim.x + threadIdx.x;
  if (e >= ET) return;
  int src, dst;
  if (e < E_EDGES) { src = ei[e]; dst = ei[E_EDGES + e]; }
  else { src = e - E_EDGES; dst = src; }
  int pos = atomicAdd(&cursor[dst], 1);
  csr_src[pos] = src;
}

// ---------------- 2-term split-bf16 MFMA GEMM: h = A @ (Whi+Wlo)^T ----------------
// BM=64 (782 blocks), BN=256, BK=32. 4 waves; wave w = head w, 64x64 sub-tile.
// Writes h in HEAD-MAJOR layout: hbuf16[head][node][64] (agg gathers per-head).

template <int K>
__global__ __launch_bounds__(256) void mfma_gemm_kernel(
    const unsigned short* __restrict__ A,
    const unsigned short* __restrict__ Whi, const unsigned short* __restrict__ Wlo,
    const float* __restrict__ a_s, const float* __restrict__ a_d,
    _Float16* __restrict__ hbuf16, float* __restrict__ als, float* __restrict__ ald) {
  __shared__ unsigned short As[4 * 64 * 8];       // 4 KB
  __shared__ unsigned short Bs[2][4 * 256 * 8];   // 32 KB

  int t = threadIdx.x;
  int mt = blockIdx.x;
  int w = t >> 6, lane = t & 63, lr = lane & 15, kg = lane >> 4;
  int srow = t >> 2, skg = t & 3;

  f32x4 acc[4][4];
#pragma unroll
  for (int m = 0; m < 4; m++)
#pragma unroll
    for (int nf = 0; nf < 4; nf++) {
      f32x4 z = {0.f, 0.f, 0.f, 0.f};
      acc[m][nf] = z;
    }

  int agrow = mt * 64 + srow;
  bool avalid = agrow < N_NODES;

  for (int k0 = 0; k0 < K; k0 += 32) {
    us8 va;
    if (avalid) {
      va = *(const us8*)&A[(size_t)agrow * K + k0 + skg * 8];
    } else {
      us8 z = {0, 0, 0, 0, 0, 0, 0, 0};
      va = z;
    }
    us8 vb0[4], vb1[4];
#pragma unroll
    for (int c = 0; c < 4; c++) {
      int n = srow + 64 * c;
      vb0[c] = *(const us8*)&Whi[(size_t)n * K + k0 + skg * 8];
      vb1[c] = *(const us8*)&Wlo[(size_t)n * K + k0 + skg * 8];
    }
    __syncthreads();
    *(us8*)&As[(skg * 64 + srow) * 8] = va;
#pragma unroll
    for (int c = 0; c < 4; c++) {
      int n = srow + 64 * c;
      *(us8*)&Bs[0][(skg * 256 + n) * 8] = vb0[c];
      *(us8*)&Bs[1][(skg * 256 + n) * 8] = vb1[c];
    }
    __syncthreads();

    us8 bh[4], bl[4];
#pragma unroll
    for (int nf = 0; nf < 4; nf++) {
      int n = w * 64 + nf * 16 + lr;
      bh[nf] = *(us8*)&Bs[0][(kg * 256 + n) * 8];
      bl[nf] = *(us8*)&Bs[1][(kg * 256 + n) * 8];
    }
#pragma unroll
    for (int m = 0; m < 4; m++) {
      int row = m * 16 + lr;
      us8 ah = *(us8*)&As[(kg * 64 + row) * 8];
#pragma unroll
      for (int nf = 0; nf < 4; nf++) {
        acc[m][nf] = MFMA16(ah, bh[nf], acc[m][nf]);
        acc[m][nf] = MFMA16(ah, bl[nf], acc[m][nf]);
      }
    }
  }

  // epilogue: store h (fp16, head-major) + reduce als/ald (scaled by log2e).
  // C layout: col = nf*16 + lr, row = m*16 + kg*4 + r
  int head = w;
  _Float16* hout = hbuf16 + (size_t)head * ((size_t)N_NODES * HID);
  float asv[4], adv[4];
#pragma unroll
  for (int nf = 0; nf < 4; nf++) {
    asv[nf] = a_s[head * HID + nf * 16 + lr];
    adv[nf] = a_d[head * HID + nf * 16 + lr];
  }
#pragma unroll
  for (int m = 0; m < 4; m++) {
#pragma unroll
    for (int r = 0; r < 4; r++) {
      int grow = mt * 64 + m * 16 + kg * 4 + r;
      float ps = 0.f, pd = 0.f;
#pragma unroll
      for (int nf = 0; nf < 4; nf++) {
        float v = acc[m][nf][r];
        ps += v * asv[nf];
        pd += v * adv[nf];
        if (grow < N_NODES)
          hout[(size_t)grow * HID + nf * 16 + lr] = (_Float16)v;
      }
#pragma unroll
      for (int msk = 1; msk < 16; msk <<= 1) {
        ps += __shfl_xor(ps, msk, 64);
        pd += __shfl_xor(pd, msk, 64);
      }
      if (lr == 0 && grow < N_NODES) {
        als[grow * HEADS + head] = ps * L2E;
        ald[grow * HEADS + head] = pd * L2E;
      }
    }
  }
}

// ---------------- per-head-pass softmax + aggregate ----------------
// Wave = 4 node-groups x 16 lanes. Outer loop over heads: per-pass random gather
// footprint = N*64*2B = 6.4 MB (vs 25.6 MB node-major) -> better per-XCD L2 hit.
// Each group's divergent loop length = its own degree (exec-mask handles it; no
// clamp waste, no extra VGPRs). 4 independent gather streams per wave.
// MODE 0: relu + bf16 output (layers 1,2). MODE 1: bias + fused mean-pool (layer 3).
// Grid: N_NODES/16 = 3125 blocks exactly.

template <int MODE>
__global__ __launch_bounds__(256) void agg_kernel(
    const _Float16* __restrict__ hbuf16, const float* __restrict__ alsE,
    const float* __restrict__ aldE, const int* __restrict__ rowptr,
    const int* __restrict__ csr_src, const float* __restrict__ bias,
    unsigned short* __restrict__ ohi, float* __restrict__ pooled,
    const int* __restrict__ batch) {
  __shared__ float pacc[16][64];
  __shared__ int pg[16];
  int wave = threadIdx.x >> 6;
  int lane = threadIdx.x & 63;
  int grp = lane >> 4;
  int lr = lane & 15;
  int nb = wave * 4 + grp;              // node index within block (0..15)
  int v = blockIdx.x * 16 + nb;
  int beg = rowptr[v];
  int n = rowptr[v + 1] - beg;
  const int* sp = csr_src + beg;
  if (MODE == 1 && lane == 0) {
    pg[wave * 4] = batch[v];
    pg[wave * 4 + 1] = batch[v + 1];
    pg[wave * 4 + 2] = batch[v + 2];
    pg[wave * 4 + 3] = batch[v + 3];
  }

#pragma unroll
  for (int p = 0; p < HEADS; p++) {
    float aldv = aldE[(unsigned)v * HEADS + p];
    float den = 0.f;
    f32x4 acc = {0.f, 0.f, 0.f, 0.f};
    const _Float16* hp = hbuf16 + (size_t)p * ((size_t)N_NODES * HID) + (lr << 2);
#pragma unroll 2
    for (int i = 0; i < n; i++) {
      int s = sp[i];
      float a = alsE[((unsigned)s << 2) + p] + aldv;
      a = fmaxf(a, SLOPE * a);
      float ex = __builtin_amdgcn_exp2f(a);
      den += ex;
      h16x4 hv = *(const h16x4*)(hp + ((unsigned)s << 6));
      acc[0] += (float)hv[0] * ex;
      acc[1] += (float)hv[1] * ex;
      acc[2] += (float)hv[2] * ex;
      acc[3] += (float)hv[3] * ex;
    }
    float inv = 1.0f / (den + 1e-16f);
    float4 bv = *(const float4*)&bias[p * HID + lr * 4];
    float o[4];
    o[0] = acc[0] * inv + bv.x;
    o[1] = acc[1] * inv + bv.y;
    o[2] = acc[2] * inv + bv.z;
    o[3] = acc[3] * inv + bv.w;

    if (MODE == 0) {
      us4 h;
#pragma unroll
      for (int j = 0; j < 4; j++) h[j] = f2bf_rne(fmaxf(o[j], 0.f));
      *(us4*)&ohi[(size_t)v * HC + p * HID + lr * 4] = h;
    } else {
      f32x4 ov = {o[0], o[1], o[2], o[3]};
      *(f32x4*)&pacc[nb][lr * 4] = ov;
      __syncthreads();
      int t = threadIdx.x;
      if (t < 64) {
        float s = pacc[0][t];
        int gcur = pg[0];
#pragma unroll
        for (int k = 1; k < 16; k++) {
          if (pg[k] != gcur) {
            atomicAdd(&pooled[gcur * HC + p * HID + t], s);
            s = 0.f;
            gcur = pg[k];
          }
          s += pacc[k][t];
        }
        atomicAdd(&pooled[gcur * HC + p * HID + t], s);
      }
      __syncthreads();
    }
  }
}

// ---------------- MLP head (fused mean-divide) ----------------

__global__ __launch_bounds__(64) void mlp_kernel(const float* __restrict__ pooled_sum,
                                                 const int* __restrict__ batch,
                                                 const float* __restrict__ w1,
                                                 const float* __restrict__ b1,
                                                 const float* __restrict__ w2,
                                                 const float* __restrict__ b2,
                                                 float* __restrict__ out) {
  int g = blockIdx.x;
  int j = threadIdx.x;
  int lo = 0, hi = N_NODES;
  while (lo < hi) { int mid = (lo + hi) >> 1; if (batch[mid] < g) lo = mid + 1; else hi = mid; }
  int start = lo;
  hi = N_NODES;
  while (lo < hi) { int mid = (lo + hi) >> 1; if (batch[mid] < g + 1) lo = mid + 1; else hi = mid; }
  float invc = 1.0f / fmaxf((float)(lo - start), 1.0f);
  __shared__ float z[HID];
  float acc = 0.f;
  for (int k = 0; k < HC; k++) acc += pooled_sum[g * HC + k] * w1[j * HC + k];
  z[j] = fmaxf(acc * invc + b1[j], 0.f);
  __syncthreads();
  if (j < NC) {
    float o = b2[j];
    for (int k = 0; k < HID; k++) o += z[k] * w2[j * HID + k];
    out[g * NC + j] = o;
  }
}

// ---------------- launch ----------------

extern "C" void kernel_launch(void* const* d_in, const int* in_sizes, int n_in,
                              void* d_out, int out_size, void* d_ws, size_t ws_size,
                              hipStream_t stream) {
  const float* x    = (const float*)d_in[0];
  const int*   ei   = (const int*)d_in[1];
  const int*   batch= (const int*)d_in[2];
  const float* W1   = (const float*)d_in[3];
  const float* as1  = (const float*)d_in[4];
  const float* ad1  = (const float*)d_in[5];
  const float* b1   = (const float*)d_in[6];
  const float* W2   = (const float*)d_in[7];
  const float* as2  = (const float*)d_in[8];
  const float* ad2  = (const float*)d_in[9];
  const float* b2   = (const float*)d_in[10];
  const float* W3   = (const float*)d_in[11];
  const float* as3  = (const float*)d_in[12];
  const float* ad3  = (const float*)d_in[13];
  const float* b3   = (const float*)d_in[14];
  const float* fc1w = (const float*)d_in[15];
  const float* fc1b = (const float*)d_in[16];
  const float* fc2w = (const float*)d_in[17];
  const float* fc2b = (const float*)d_in[18];
  float* out = (float*)d_out;

  char* ws = (char*)d_ws;
  size_t off = 0;
  _Float16* hbuf16 = (_Float16*)(ws + off); off += (size_t)N_NODES * HC * 2;
  unsigned short* ahi = (unsigned short*)(ws + off); off += (size_t)N_NODES * HC * 2;
  unsigned short* xhi = (unsigned short*)(ws + off); off += (size_t)N_NODES * IN_F * 2;
  unsigned short* w1h = (unsigned short*)(ws + off); off += (size_t)HC * IN_F * 2;
  unsigned short* w1l = (unsigned short*)(ws + off); off += (size_t)HC * IN_F * 2;
  unsigned short* w2h = (unsigned short*)(ws + off); off += (size_t)HC * HC * 2;
  unsigned short* w2l = (unsigned short*)(ws + off); off += (size_t)HC * HC * 2;
  unsigned short* w3h = (unsigned short*)(ws + off); off += (size_t)HC * HC * 2;
  unsigned short* w3l = (unsigned short*)(ws + off); off += (size_t)HC * HC * 2;
  float* als    = (float*)(ws + off); off += (size_t)N_NODES * HEADS * 4;
  float* ald    = (float*)(ws + off); off += (size_t)N_NODES * HEADS * 4;
  float* pooled = (float*)(ws + off); off += (size_t)G_GRAPHS * HC * 4;
  int*   cnt    = (int*)(ws + off);   off += (size_t)N_NODES * 4;
  int*   cursor = (int*)(ws + off);   off += (size_t)N_NODES * 4;
  int*   csrsrc = (int*)(ws + off);   off += (size_t)ET * 4;
  int*   rowptr = (int*)(ws + off);   off += (size_t)(N_NODES + 1) * 4;
  int*   partial= (int*)(ws + off);   off += 256 * 4;

  // --- fused splits (independent of CSR) ---
  split_all_kernel<<<(QTOT + 255) / 256, 256, 0, stream>>>(
      x, W1, W2, W3, xhi, w1h, w1l, w2h, w2l, w3h, w3l);

  // --- CSR build ---
  hipMemsetAsync(cnt, 0, (size_t)N_NODES * 4, stream);
  hipMemsetAsync(pooled, 0, (size_t)G_GRAPHS * HC * 4, stream);
  count_kernel<<<(ET + 255) / 256, 256, 0, stream>>>(ei, cnt);
  scan1_kernel<<<SCAN_BLOCKS, 256, 0, stream>>>(cnt, cursor, partial);
  scan2_kernel<<<1, 256, 0, stream>>>(partial);
  scan3_kernel<<<SCAN_BLOCKS, 256, 0, stream>>>(cnt, cursor, partial, rowptr, cursor);
  scatter_kernel<<<(ET + 255) / 256, 256, 0, stream>>>(ei, cursor, csrsrc);

  dim3 gemm_grid((N_NODES + 63) / 64);
  int agg_grid = N_NODES / 16;  // exact: 50000 % 16 == 0

  // --- layer 1 ---
  mfma_gemm_kernel<IN_F><<<gemm_grid, 256, 0, stream>>>(xhi, w1h, w1l, as1, ad1, hbuf16, als, ald);
  agg_kernel<0><<<agg_grid, 256, 0, stream>>>(hbuf16, als, ald, rowptr, csrsrc, b1, ahi, nullptr, nullptr);
  // --- layer 2 ---
  mfma_gemm_kernel<HC><<<gemm_grid, 256, 0, stream>>>(ahi, w2h, w2l, as2, ad2, hbuf16, als, ald);
  agg_kernel<0><<<agg_grid, 256, 0, stream>>>(hbuf16, als, ald, rowptr, csrsrc, b2, ahi, nullptr, nullptr);
  // --- layer 3 (fused mean-pool accumulate) ---
  mfma_gemm_kernel<HC><<<gemm_grid, 256, 0, stream>>>(ahi, w3h, w3l, as3, ad3, hbuf16, als, ald);
  agg_kernel<1><<<agg_grid, 256, 0, stream>>>(hbuf16, als, ald, rowptr, csrsrc, b3, nullptr, pooled, batch);

  // --- MLP (with fused mean divide) ---
  mlp_kernel<<<G_GRAPHS, 64, 0, stream>>>(pooled, batch, fc1w, fc1b, fc2w, fc2b, out);
}

// Round 11
// 457.750 us; speedup vs baseline: 1.0977x; 1.0977x over previous
//
#include <hip/hip_runtime.h>
#include <hip/hip_bf16.h>

#define N_NODES 50000
#define E_EDGES 800000
#define ET (E_EDGES + N_NODES)
#define G_GRAPHS 64
#define IN_F 128
#define HID 64
#define HEADS 4
#define HC (HID * HEADS)
#define NC 2
#define SLOPE 0.2f
#define L2E 1.4426950408889634f

typedef float f32x4 __attribute__((ext_vector_type(4)));
typedef __bf16 bf16x8 __attribute__((ext_vector_type(8)));
typedef unsigned short us8 __attribute__((ext_vector_type(8)));
typedef unsigned short us4 __attribute__((ext_vector_type(4)));
typedef _Float16 h16x4 __attribute__((ext_vector_type(4)));

#define MFMA16(a, b, c) \
  __builtin_amdgcn_mfma_f32_16x16x32_bf16(__builtin_bit_cast(bf16x8, (a)), \
                                          __builtin_bit_cast(bf16x8, (b)), (c), 0, 0, 0)

// async global->LDS, 16B per lane, dest = wave-uniform base + lane*16
typedef __attribute__((address_space(1))) void gvoid;
typedef __attribute__((address_space(3))) void lvoid;
#define GLD16(g, l) \
  __builtin_amdgcn_global_load_lds((gvoid*)(g), (lvoid*)(l), 16, 0, 0)

__device__ inline unsigned short f2bf_rne(float f) {
  unsigned u = __builtin_bit_cast(unsigned, f);
  u += 0x7fffu + ((u >> 16) & 1u);
  return (unsigned short)(u >> 16);
}
__device__ inline float bf2f(unsigned short h) {
  unsigned u = ((unsigned)h) << 16;
  return __builtin_bit_cast(float, u);
}

// ---------------- fused split/cast kernel ----------------

__device__ inline void split4(const float* __restrict__ in, unsigned short* __restrict__ hi,
                              unsigned short* __restrict__ lo, int i) {
  float4 v = *(const float4*)&in[i];
  float f[4] = {v.x, v.y, v.z, v.w};
  us4 h, l;
#pragma unroll
  for (int j = 0; j < 4; j++) {
    unsigned short hb = f2bf_rne(f[j]);
    h[j] = hb;
    l[j] = f2bf_rne(f[j] - bf2f(hb));
  }
  *(us4*)&hi[i] = h;
  *(us4*)&lo[i] = l;
}

#define QX (N_NODES * IN_F / 4)
#define QW1 (HC * IN_F / 4)
#define QW2 (HC * HC / 4)
#define QTOT (QX + QW1 + 2 * QW2)

__global__ __launch_bounds__(256) void split_all_kernel(
    const float* __restrict__ x, const float* __restrict__ W1,
    const float* __restrict__ W2, const float* __restrict__ W3,
    unsigned short* __restrict__ xhi,
    unsigned short* __restrict__ w1h, unsigned short* __restrict__ w1l,
    unsigned short* __restrict__ w2h, unsigned short* __restrict__ w2l,
    unsigned short* __restrict__ w3h, unsigned short* __restrict__ w3l) {
  int q = blockIdx.x * 256 + threadIdx.x;
  if (q < QX) {
    int i = q * 4;
    float4 v = *(const float4*)&x[i];
    float f[4] = {v.x, v.y, v.z, v.w};
    us4 h;
#pragma unroll
    for (int j = 0; j < 4; j++) h[j] = f2bf_rne(f[j]);
    *(us4*)&xhi[i] = h;
  } else if (q < QX + QW1) {
    split4(W1, w1h, w1l, (q - QX) * 4);
  } else if (q < QX + QW1 + QW2) {
    split4(W2, w2h, w2l, (q - QX - QW1) * 4);
  } else {
    split4(W3, w3h, w3l, (q - QX - QW1 - QW2) * 4);
  }
}

// ---------------- CSR build ----------------

__global__ void count_kernel(const int* __restrict__ ei, int* __restrict__ cnt) {
  int e = blockIdx.x * blockDim.x + threadIdx.x;
  if (e >= ET) return;
  int dst = (e < E_EDGES) ? ei[E_EDGES + e] : (e - E_EDGES);
  atomicAdd(&cnt[dst], 1);
}

#define SCAN_BLOCKS ((N_NODES + 255) / 256)

__global__ __launch_bounds__(256) void scan1_kernel(const int* __restrict__ cnt,
                                                    int* __restrict__ incl_buf,
                                                    int* __restrict__ partial) {
  __shared__ int ws[4];
  int tid = threadIdx.x, b = blockIdx.x;
  int wave = tid >> 6, lane = tid & 63;
  int i = b * 256 + tid;
  int v = (i < N_NODES) ? cnt[i] : 0;
  int x = v;
#pragma unroll
  for (int off = 1; off < 64; off <<= 1) {
    int t = __shfl_up(x, off, 64);
    if (lane >= off) x += t;
  }
  if (lane == 63) ws[wave] = x;
  __syncthreads();
  if (tid == 0) {
    int s = 0;
#pragma unroll
    for (int w = 0; w < 4; w++) { int t = ws[w]; ws[w] = s; s += t; }
    partial[b] = s;
  }
  __syncthreads();
  if (i < N_NODES) incl_buf[i] = x + ws[wave];
}

__global__ __launch_bounds__(256) void scan2_kernel(int* __restrict__ partial) {
  __shared__ int ws[4];
  int tid = threadIdx.x;
  int wave = tid >> 6, lane = tid & 63;
  int v = (tid < SCAN_BLOCKS) ? partial[tid] : 0;
  int x = v;
#pragma unroll
  for (int off = 1; off < 64; off <<= 1) {
    int t = __shfl_up(x, off, 64);
    if (lane >= off) x += t;
  }
  if (lane == 63) ws[wave] = x;
  __syncthreads();
  if (tid == 0) {
    int s = 0;
#pragma unroll
    for (int w = 0; w < 4; w++) { int t = ws[w]; ws[w] = s; s += t; }
  }
  __syncthreads();
  partial[tid] = x + ws[wave] - v;
}

__global__ __launch_bounds__(256) void scan3_kernel(const int* __restrict__ cnt,
                                                    int* __restrict__ incl_buf,
                                                    const int* __restrict__ partial,
                                                    int* __restrict__ rowptr,
                                                    int* __restrict__ cursor) {
  int tid = threadIdx.x, b = blockIdx.x;
  int i = b * 256 + tid;
  if (i >= N_NODES) return;
  int incl = incl_buf[i] + partial[b];
  rowptr[i + 1] = incl;
  cursor[i] = incl - cnt[i];
  if (i == 0) rowptr[0] = 0;
}

__global__ void scatter_kernel(const int* __restrict__ ei, int* __restrict__ cursor,
                               int* __restrict__ csr_src) {
  int e = blockIdx.x * blockDim.x + threadIdx.x;
  if (e >= ET) return;
  int src, dst;
  if (e < E_EDGES) { src = ei[e]; dst = ei[E_EDGES + e]; }
  else { src = e - E_EDGES; dst = src; }
  int pos = atomicAdd(&cursor[dst], 1);
  csr_src[pos] = src;
}

// ---------------- 2-term split-bf16 MFMA GEMM via global_load_lds ----------------
// BM=64 (782 blocks), BN=256, BK=32. 4 waves; wave w = head w, 64x64 sub-tile.
// Staging: async global->LDS, 16B/lane, lane-linear chunk layout:
//   B chunk c = (plane*4+kg)*256 + n  == w*512 + j*64 + lane   (8 issues/thread)
//   A chunk c = kg*64 + row           == w*64 + lane           (1 issue/thread)
// Tail block (mt=781) loads garbage A rows >= N: harmless (MFMA rows independent;
// h/als/ald for rows >= N are never read; addresses stay inside workspace).

template <int K>
__global__ __launch_bounds__(256) void mfma_gemm_kernel(
    const unsigned short* __restrict__ A,
    const unsigned short* __restrict__ Whi, const unsigned short* __restrict__ Wlo,
    const float* __restrict__ a_s, const float* __restrict__ a_d,
    _Float16* __restrict__ hbuf16, float* __restrict__ als, float* __restrict__ ald) {
  __shared__ unsigned short As[4 * 64 * 8];      // 4 KB  (chunk = kg*64+row)
  __shared__ unsigned short Bs[2 * 4 * 256 * 8]; // 32 KB (chunk = (plane*4+kg)*256+n)

  int t = threadIdx.x;
  int mt = blockIdx.x;
  int w = t >> 6, lane = t & 63, lr = lane & 15, kg = lane >> 4;

  f32x4 acc[4][4];
#pragma unroll
  for (int m = 0; m < 4; m++)
#pragma unroll
    for (int nf = 0; nf < 4; nf++) {
      f32x4 z = {0.f, 0.f, 0.f, 0.f};
      acc[m][nf] = z;
    }

  for (int k0 = 0; k0 < K; k0 += 32) {
    __syncthreads();  // previous iteration's ds_reads complete before overwrite
    // ---- B planes: 8 async issues per thread
#pragma unroll
    for (int j = 0; j < 8; j++) {
      int c = w * 512 + j * 64 + lane;
      int plane = c >> 10;
      int bkg = (c >> 8) & 3;
      int n = c & 255;
      const unsigned short* gsrc =
          (plane ? Wlo : Whi) + (size_t)n * K + k0 + bkg * 8;
      GLD16(gsrc, &Bs[(size_t)(w * 512 + j * 64) * 8]);
    }
    // ---- A: 1 async issue per thread (chunk = w*64+lane -> kg=w, row=lane)
    {
      const unsigned short* gsrc = A + (size_t)(mt * 64 + lane) * K + k0 + w * 8;
      GLD16(gsrc, &As[(size_t)(w * 64) * 8]);
    }
    __syncthreads();  // compiler drains vmcnt(0) before barrier -> LDS ready

    us8 bh[4], bl[4];
#pragma unroll
    for (int nf = 0; nf < 4; nf++) {
      int n = w * 64 + nf * 16 + lr;
      bh[nf] = *(us8*)&Bs[(size_t)(kg * 256 + n) * 8];
      bl[nf] = *(us8*)&Bs[(size_t)((4 + kg) * 256 + n) * 8];
    }
#pragma unroll
    for (int m = 0; m < 4; m++) {
      int row = m * 16 + lr;
      us8 ah = *(us8*)&As[(size_t)(kg * 64 + row) * 8];
#pragma unroll
      for (int nf = 0; nf < 4; nf++) {
        acc[m][nf] = MFMA16(ah, bh[nf], acc[m][nf]);
        acc[m][nf] = MFMA16(ah, bl[nf], acc[m][nf]);
      }
    }
  }

  // epilogue: store h (fp16, node-major) + reduce als/ald (scaled by log2e).
  // C layout: col = nf*16 + lr, row = m*16 + kg*4 + r
  int head = w;
  float asv[4], adv[4];
#pragma unroll
  for (int nf = 0; nf < 4; nf++) {
    asv[nf] = a_s[head * HID + nf * 16 + lr];
    adv[nf] = a_d[head * HID + nf * 16 + lr];
  }
#pragma unroll
  for (int m = 0; m < 4; m++) {
#pragma unroll
    for (int r = 0; r < 4; r++) {
      int grow = mt * 64 + m * 16 + kg * 4 + r;
      float ps = 0.f, pd = 0.f;
#pragma unroll
      for (int nf = 0; nf < 4; nf++) {
        float v = acc[m][nf][r];
        ps += v * asv[nf];
        pd += v * adv[nf];
        if (grow < N_NODES)
          hbuf16[(size_t)grow * HC + head * 64 + nf * 16 + lr] = (_Float16)v;
      }
#pragma unroll
      for (int msk = 1; msk < 16; msk <<= 1) {
        ps += __shfl_xor(ps, msk, 64);
        pd += __shfl_xor(pd, msk, 64);
      }
      if (lr == 0 && grow < N_NODES) {
        als[grow * HEADS + head] = ps * L2E;
        ald[grow * HEADS + head] = pd * L2E;
      }
    }
  }
}

// ---------------- dual-stream per-destination softmax + aggregate (R7 keeper) ----------------
// One wave handles TWO dst nodes with interleaved edge streams: 2 independent
// gathers in flight, low VGPR (28), occupancy-preserving. Best measured: 69 us.
// MODE 0: relu + bf16 output (layers 1,2). MODE 1: bias + fused mean-pool (layer 3).
// Grid: N_NODES/8 = 6250 blocks exactly.

template <int MODE>
__global__ __launch_bounds__(256) void agg_kernel(
    const _Float16* __restrict__ hbuf16, const float* __restrict__ alsE,
    const float* __restrict__ aldE, const int* __restrict__ rowptr,
    const int* __restrict__ csr_src, const float* __restrict__ bias,
    unsigned short* __restrict__ ohi, float* __restrict__ pooled,
    const int* __restrict__ batch) {
  int wave = threadIdx.x >> 6;
  int lane = threadIdx.x & 63;
  int v0 = blockIdx.x * 8 + wave * 2;
  int v1 = v0 + 1;
  int head = lane >> 4;
  float ald0 = aldE[(unsigned)v0 * HEADS + head];
  float ald1 = aldE[(unsigned)v1 * HEADS + head];
  int beg0 = rowptr[v0], n0 = rowptr[v0 + 1] - beg0;
  int beg1 = rowptr[v1], n1 = rowptr[v1 + 1] - beg1;
  int n = max(n0, n1);

  float den0 = 0.f, den1 = 0.f;
  f32x4 acc0 = {0.f, 0.f, 0.f, 0.f};
  f32x4 acc1 = {0.f, 0.f, 0.f, 0.f};
  const _Float16* hp = hbuf16 + (lane << 2);
#pragma unroll 2
  for (int i = 0; i < n; i++) {
    int s0 = csr_src[beg0 + min(i, n0 - 1)];
    int s1 = csr_src[beg1 + min(i, n1 - 1)];
    float a0 = alsE[(unsigned)s0 * HEADS + head] + ald0;
    float a1 = alsE[(unsigned)s1 * HEADS + head] + ald1;
    a0 = fmaxf(a0, SLOPE * a0);
    a1 = fmaxf(a1, SLOPE * a1);
    float ex0 = (i < n0) ? __builtin_amdgcn_exp2f(a0) : 0.f;
    float ex1 = (i < n1) ? __builtin_amdgcn_exp2f(a1) : 0.f;
    h16x4 h0 = *(const h16x4*)(hp + ((unsigned)s0 << 8));
    h16x4 h1 = *(const h16x4*)(hp + ((unsigned)s1 << 8));
    den0 += ex0; den1 += ex1;
    acc0[0] += (float)h0[0] * ex0; acc0[1] += (float)h0[1] * ex0;
    acc0[2] += (float)h0[2] * ex0; acc0[3] += (float)h0[3] * ex0;
    acc1[0] += (float)h1[0] * ex1; acc1[1] += (float)h1[1] * ex1;
    acc1[2] += (float)h1[2] * ex1; acc1[3] += (float)h1[3] * ex1;
  }
  float inv0 = 1.0f / (den0 + 1e-16f);
  float inv1 = 1.0f / (den1 + 1e-16f);
  float4 bv = *(const float4*)&bias[lane * 4];
  float o0[4], o1[4];
  o0[0] = acc0[0] * inv0 + bv.x; o0[1] = acc0[1] * inv0 + bv.y;
  o0[2] = acc0[2] * inv0 + bv.z; o0[3] = acc0[3] * inv0 + bv.w;
  o1[0] = acc1[0] * inv1 + bv.x; o1[1] = acc1[1] * inv1 + bv.y;
  o1[2] = acc1[2] * inv1 + bv.z; o1[3] = acc1[3] * inv1 + bv.w;

  if (MODE == 0) {
    us4 h0, h1;
#pragma unroll
    for (int j = 0; j < 4; j++) {
      h0[j] = f2bf_rne(fmaxf(o0[j], 0.f));
      h1[j] = f2bf_rne(fmaxf(o1[j], 0.f));
    }
    *(us4*)&ohi[(size_t)v0 * HC + lane * 4] = h0;
    *(us4*)&ohi[(size_t)v1 * HC + lane * 4] = h1;
  } else {
    __shared__ float pacc[8][HC];
    __shared__ int pg[8];
    f32x4 ov0 = {o0[0], o0[1], o0[2], o0[3]};
    f32x4 ov1 = {o1[0], o1[1], o1[2], o1[3]};
    *(f32x4*)&pacc[wave * 2][lane * 4] = ov0;
    *(f32x4*)&pacc[wave * 2 + 1][lane * 4] = ov1;
    if (lane == 0) {
      pg[wave * 2] = batch[v0];
      pg[wave * 2 + 1] = batch[v1];
    }
    __syncthreads();
    int c = threadIdx.x;
    float s = pacc[0][c];
    int gcur = pg[0];
#pragma unroll
    for (int wv = 1; wv < 8; wv++) {
      if (pg[wv] != gcur) {
        atomicAdd(&pooled[gcur * HC + c], s);
        s = 0.f;
        gcur = pg[wv];
      }
      s += pacc[wv][c];
    }
    atomicAdd(&pooled[gcur * HC + c], s);
  }
}

// ---------------- MLP head (fused mean-divide) ----------------

__global__ __launch_bounds__(64) void mlp_kernel(const float* __restrict__ pooled_sum,
                                                 const int* __restrict__ batch,
                                                 const float* __restrict__ w1,
                                                 const float* __restrict__ b1,
                                                 const float* __restrict__ w2,
                                                 const float* __restrict__ b2,
                                                 float* __restrict__ out) {
  int g = blockIdx.x;
  int j = threadIdx.x;
  int lo = 0, hi = N_NODES;
  while (lo < hi) { int mid = (lo + hi) >> 1; if (batch[mid] < g) lo = mid + 1; else hi = mid; }
  int start = lo;
  hi = N_NODES;
  while (lo < hi) { int mid = (lo + hi) >> 1; if (batch[mid] < g + 1) lo = mid + 1; else hi = mid; }
  float invc = 1.0f / fmaxf((float)(lo - start), 1.0f);
  __shared__ float z[HID];
  float acc = 0.f;
  for (int k = 0; k < HC; k++) acc += pooled_sum[g * HC + k] * w1[j * HC + k];
  z[j] = fmaxf(acc * invc + b1[j], 0.f);
  __syncthreads();
  if (j < NC) {
    float o = b2[j];
    for (int k = 0; k < HID; k++) o += z[k] * w2[j * HID + k];
    out[g * NC + j] = o;
  }
}

// ---------------- launch ----------------

extern "C" void kernel_launch(void* const* d_in, const int* in_sizes, int n_in,
                              void* d_out, int out_size, void* d_ws, size_t ws_size,
                              hipStream_t stream) {
  const float* x    = (const float*)d_in[0];
  const int*   ei   = (const int*)d_in[1];
  const int*   batch= (const int*)d_in[2];
  const float* W1   = (const float*)d_in[3];
  const float* as1  = (const float*)d_in[4];
  const float* ad1  = (const float*)d_in[5];
  const float* b1   = (const float*)d_in[6];
  const float* W2   = (const float*)d_in[7];
  const float* as2  = (const float*)d_in[8];
  const float* ad2  = (const float*)d_in[9];
  const float* b2   = (const float*)d_in[10];
  const float* W3   = (const float*)d_in[11];
  const float* as3  = (const float*)d_in[12];
  const float* ad3  = (const float*)d_in[13];
  const float* b3   = (const float*)d_in[14];
  const float* fc1w = (const float*)d_in[15];
  const float* fc1b = (const float*)d_in[16];
  const float* fc2w = (const float*)d_in[17];
  const float* fc2b = (const float*)d_in[18];
  float* out = (float*)d_out;

  char* ws = (char*)d_ws;
  size_t off = 0;
  _Float16* hbuf16 = (_Float16*)(ws + off); off += (size_t)N_NODES * HC * 2;
  unsigned short* ahi = (unsigned short*)(ws + off); off += (size_t)N_NODES * HC * 2;
  unsigned short* xhi = (unsigned short*)(ws + off); off += (size_t)N_NODES * IN_F * 2;
  unsigned short* w1h = (unsigned short*)(ws + off); off += (size_t)HC * IN_F * 2;
  unsigned short* w1l = (unsigned short*)(ws + off); off += (size_t)HC * IN_F * 2;
  unsigned short* w2h = (unsigned short*)(ws + off); off += (size_t)HC * HC * 2;
  unsigned short* w2l = (unsigned short*)(ws + off); off += (size_t)HC * HC * 2;
  unsigned short* w3h = (unsigned short*)(ws + off); off += (size_t)HC * HC * 2;
  unsigned short* w3l = (unsigned short*)(ws + off); off += (size_t)HC * HC * 2;
  float* als    = (float*)(ws + off); off += (size_t)N_NODES * HEADS * 4;
  float* ald    = (float*)(ws + off); off += (size_t)N_NODES * HEADS * 4;
  float* pooled = (float*)(ws + off); off += (size_t)G_GRAPHS * HC * 4;
  int*   cnt    = (int*)(ws + off);   off += (size_t)N_NODES * 4;
  int*   cursor = (int*)(ws + off);   off += (size_t)N_NODES * 4;
  int*   csrsrc = (int*)(ws + off);   off += (size_t)ET * 4;
  int*   rowptr = (int*)(ws + off);   off += (size_t)(N_NODES + 1) * 4;
  int*   partial= (int*)(ws + off);   off += 256 * 4;

  // --- fused splits (independent of CSR) ---
  split_all_kernel<<<(QTOT + 255) / 256, 256, 0, stream>>>(
      x, W1, W2, W3, xhi, w1h, w1l, w2h, w2l, w3h, w3l);

  // --- CSR build ---
  hipMemsetAsync(cnt, 0, (size_t)N_NODES * 4, stream);
  hipMemsetAsync(pooled, 0, (size_t)G_GRAPHS * HC * 4, stream);
  count_kernel<<<(ET + 255) / 256, 256, 0, stream>>>(ei, cnt);
  scan1_kernel<<<SCAN_BLOCKS, 256, 0, stream>>>(cnt, cursor, partial);
  scan2_kernel<<<1, 256, 0, stream>>>(partial);
  scan3_kernel<<<SCAN_BLOCKS, 256, 0, stream>>>(cnt, cursor, partial, rowptr, cursor);
  scatter_kernel<<<(ET + 255) / 256, 256, 0, stream>>>(ei, cursor, csrsrc);

  dim3 gemm_grid((N_NODES + 63) / 64);
  int agg_grid = N_NODES / 8;  // exact: 50000 % 8 == 0

  // --- layer 1 ---
  mfma_gemm_kernel<IN_F><<<gemm_grid, 256, 0, stream>>>(xhi, w1h, w1l, as1, ad1, hbuf16, als, ald);
  agg_kernel<0><<<agg_grid, 256, 0, stream>>>(hbuf16, als, ald, rowptr, csrsrc, b1, ahi, nullptr, nullptr);
  // --- layer 2 ---
  mfma_gemm_kernel<HC><<<gemm_grid, 256, 0, stream>>>(ahi, w2h, w2l, as2, ad2, hbuf16, als, ald);
  agg_kernel<0><<<agg_grid, 256, 0, stream>>>(hbuf16, als, ald, rowptr, csrsrc, b2, ahi, nullptr, nullptr);
  // --- layer 3 (fused mean-pool accumulate) ---
  mfma_gemm_kernel<HC><<<gemm_grid, 256, 0, stream>>>(ahi, w3h, w3l, as3, ad3, hbuf16, als, ald);
  agg_kernel<1><<<agg_grid, 256, 0, stream>>>(hbuf16, als, ald, rowptr, csrsrc, b3, nullptr, pooled, batch);

  // --- MLP (with fused mean divide) ---
  mlp_kernel<<<G_GRAPHS, 64, 0, stream>>>(pooled, batch, fc1w, fc1b, fc2w, fc2b, out);
}

// Round 12
// 425.542 us; speedup vs baseline: 1.1808x; 1.0757x over previous
//
#include <hip/hip_runtime.h>
#include <hip/hip_bf16.h>

#define N_NODES 50000
#define E_EDGES 800000
#define ET (E_EDGES + N_NODES)
#define G_GRAPHS 64
#define IN_F 128
#define HID 64
#define HEADS 4
#define HC (HID * HEADS)
#define NC 2
#define SLOPE 0.2f
#define L2E 1.4426950408889634f

typedef float f32x4 __attribute__((ext_vector_type(4)));
typedef __bf16 bf16x8 __attribute__((ext_vector_type(8)));
typedef unsigned short us8 __attribute__((ext_vector_type(8)));
typedef unsigned short us4 __attribute__((ext_vector_type(4)));
typedef _Float16 h16x4 __attribute__((ext_vector_type(4)));

#define MFMA16(a, b, c) \
  __builtin_amdgcn_mfma_f32_16x16x32_bf16(__builtin_bit_cast(bf16x8, (a)), \
                                          __builtin_bit_cast(bf16x8, (b)), (c), 0, 0, 0)

__device__ inline unsigned short f2bf_rne(float f) {
  unsigned u = __builtin_bit_cast(unsigned, f);
  u += 0x7fffu + ((u >> 16) & 1u);
  return (unsigned short)(u >> 16);
}
__device__ inline float bf2f(unsigned short h) {
  unsigned u = ((unsigned)h) << 16;
  return __builtin_bit_cast(float, u);
}

// ---------------- fused split/cast kernel ----------------

__device__ inline void split4(const float* __restrict__ in, unsigned short* __restrict__ hi,
                              unsigned short* __restrict__ lo, int i) {
  float4 v = *(const float4*)&in[i];
  float f[4] = {v.x, v.y, v.z, v.w};
  us4 h, l;
#pragma unroll
  for (int j = 0; j < 4; j++) {
    unsigned short hb = f2bf_rne(f[j]);
    h[j] = hb;
    l[j] = f2bf_rne(f[j] - bf2f(hb));
  }
  *(us4*)&hi[i] = h;
  *(us4*)&lo[i] = l;
}

#define QX (N_NODES * IN_F / 4)
#define QW1 (HC * IN_F / 4)
#define QW2 (HC * HC / 4)
#define QTOT (QX + QW1 + 2 * QW2)

__global__ __launch_bounds__(256) void split_all_kernel(
    const float* __restrict__ x, const float* __restrict__ W1,
    const float* __restrict__ W2, const float* __restrict__ W3,
    unsigned short* __restrict__ xhi,
    unsigned short* __restrict__ w1h, unsigned short* __restrict__ w1l,
    unsigned short* __restrict__ w2h, unsigned short* __restrict__ w2l,
    unsigned short* __restrict__ w3h, unsigned short* __restrict__ w3l) {
  int q = blockIdx.x * 256 + threadIdx.x;
  if (q < QX) {
    int i = q * 4;
    float4 v = *(const float4*)&x[i];
    float f[4] = {v.x, v.y, v.z, v.w};
    us4 h;
#pragma unroll
    for (int j = 0; j < 4; j++) h[j] = f2bf_rne(f[j]);
    *(us4*)&xhi[i] = h;
  } else if (q < QX + QW1) {
    split4(W1, w1h, w1l, (q - QX) * 4);
  } else if (q < QX + QW1 + QW2) {
    split4(W2, w2h, w2l, (q - QX - QW1) * 4);
  } else {
    split4(W3, w3h, w3l, (q - QX - QW1 - QW2) * 4);
  }
}

// ---------------- CSR build ----------------

__global__ void count_kernel(const int* __restrict__ ei, int* __restrict__ cnt) {
  int e = blockIdx.x * blockDim.x + threadIdx.x;
  if (e >= ET) return;
  int dst = (e < E_EDGES) ? ei[E_EDGES + e] : (e - E_EDGES);
  atomicAdd(&cnt[dst], 1);
}

#define SCAN_BLOCKS ((N_NODES + 255) / 256)

__global__ __launch_bounds__(256) void scan1_kernel(const int* __restrict__ cnt,
                                                    int* __restrict__ incl_buf,
                                                    int* __restrict__ partial) {
  __shared__ int ws[4];
  int tid = threadIdx.x, b = blockIdx.x;
  int wave = tid >> 6, lane = tid & 63;
  int i = b * 256 + tid;
  int v = (i < N_NODES) ? cnt[i] : 0;
  int x = v;
#pragma unroll
  for (int off = 1; off < 64; off <<= 1) {
    int t = __shfl_up(x, off, 64);
    if (lane >= off) x += t;
  }
  if (lane == 63) ws[wave] = x;
  __syncthreads();
  if (tid == 0) {
    int s = 0;
#pragma unroll
    for (int w = 0; w < 4; w++) { int t = ws[w]; ws[w] = s; s += t; }
    partial[b] = s;
  }
  __syncthreads();
  if (i < N_NODES) incl_buf[i] = x + ws[wave];
}

__global__ __launch_bounds__(256) void scan2_kernel(int* __restrict__ partial) {
  __shared__ int ws[4];
  int tid = threadIdx.x;
  int wave = tid >> 6, lane = tid & 63;
  int v = (tid < SCAN_BLOCKS) ? partial[tid] : 0;
  int x = v;
#pragma unroll
  for (int off = 1; off < 64; off <<= 1) {
    int t = __shfl_up(x, off, 64);
    if (lane >= off) x += t;
  }
  if (lane == 63) ws[wave] = x;
  __syncthreads();
  if (tid == 0) {
    int s = 0;
#pragma unroll
    for (int w = 0; w < 4; w++) { int t = ws[w]; ws[w] = s; s += t; }
  }
  __syncthreads();
  partial[tid] = x + ws[wave] - v;
}

__global__ __launch_bounds__(256) void scan3_kernel(const int* __restrict__ cnt,
                                                    int* __restrict__ incl_buf,
                                                    const int* __restrict__ partial,
                                                    int* __restrict__ rowptr,
                                                    int* __restrict__ cursor) {
  int tid = threadIdx.x, b = blockIdx.x;
  int i = b * 256 + tid;
  if (i >= N_NODES) return;
  int incl = incl_buf[i] + partial[b];
  rowptr[i + 1] = incl;
  cursor[i] = incl - cnt[i];
  if (i == 0) rowptr[0] = 0;
}

__global__ void scatter_kernel(const int* __restrict__ ei, int* __restrict__ cursor,
                               int* __restrict__ csr_src) {
  int e = blockIdx.x * blockDim.x + threadIdx.x;
  if (e >= ET) return;
  int src, dst;
  if (e < E_EDGES) { src = ei[e]; dst = ei[E_EDGES + e]; }
  else { src = e - E_EDGES; dst = src; }
  int pos = atomicAdd(&cursor[dst], 1);
  csr_src[pos] = src;
}

// ---------------- 2-term split-bf16 MFMA GEMM, register-double-buffered ----------------
// BM=64 (782 blocks), BN=256, BK=32. 4 waves; wave w = head w, 64x64 sub-tile.
// Software pipeline: prefetch tile k+1 into VGPRs DURING compute of tile k --
// HBM latency (~900cy) hides under the 12 ds_read + 32 MFMA (+barrier) of the
// current tile instead of being exposed 8x per block (R11 diagnosis).

template <int K>
__global__ __launch_bounds__(256) void mfma_gemm_kernel(
    const unsigned short* __restrict__ A,
    const unsigned short* __restrict__ Whi, const unsigned short* __restrict__ Wlo,
    const float* __restrict__ a_s, const float* __restrict__ a_d,
    _Float16* __restrict__ hbuf16, float* __restrict__ als, float* __restrict__ ald) {
  __shared__ unsigned short As[4 * 64 * 8];       // 4 KB
  __shared__ unsigned short Bs[2][4 * 256 * 8];   // 32 KB

  int t = threadIdx.x;
  int mt = blockIdx.x;
  int w = t >> 6, lane = t & 63, lr = lane & 15, kg = lane >> 4;
  int srow = t >> 2, skg = t & 3;

  f32x4 acc[4][4];
#pragma unroll
  for (int m = 0; m < 4; m++)
#pragma unroll
    for (int nf = 0; nf < 4; nf++) {
      f32x4 z = {0.f, 0.f, 0.f, 0.f};
      acc[m][nf] = z;
    }

  int agrow = mt * 64 + srow;
  bool avalid = agrow < N_NODES;

  us8 va[2], vb0[2][4], vb1[2][4];
  // prefetch tile 0 into buffer 0
  {
    if (avalid) {
      va[0] = *(const us8*)&A[(size_t)agrow * K + skg * 8];
    } else {
      us8 z = {0, 0, 0, 0, 0, 0, 0, 0};
      va[0] = z;
    }
#pragma unroll
    for (int c = 0; c < 4; c++) {
      int n = srow + 64 * c;
      vb0[0][c] = *(const us8*)&Whi[(size_t)n * K + skg * 8];
      vb1[0][c] = *(const us8*)&Wlo[(size_t)n * K + skg * 8];
    }
  }

#pragma unroll
  for (int k0 = 0; k0 < K; k0 += 32) {
    const int buf = (k0 >> 5) & 1;
    const int nbuf = buf ^ 1;
    __syncthreads();  // all waves done reading LDS from previous tile
    *(us8*)&As[(skg * 64 + srow) * 8] = va[buf];
#pragma unroll
    for (int c = 0; c < 4; c++) {
      int n = srow + 64 * c;
      *(us8*)&Bs[0][(skg * 256 + n) * 8] = vb0[buf][c];
      *(us8*)&Bs[1][(skg * 256 + n) * 8] = vb1[buf][c];
    }
    __syncthreads();  // tile visible

    // issue NEXT tile's loads -- they retire during the MFMA work below
    if (k0 + 32 < K) {
      int k1 = k0 + 32;
      if (avalid) {
        va[nbuf] = *(const us8*)&A[(size_t)agrow * K + k1 + skg * 8];
      } else {
        us8 z = {0, 0, 0, 0, 0, 0, 0, 0};
        va[nbuf] = z;
      }
#pragma unroll
      for (int c = 0; c < 4; c++) {
        int n = srow + 64 * c;
        vb0[nbuf][c] = *(const us8*)&Whi[(size_t)n * K + k1 + skg * 8];
        vb1[nbuf][c] = *(const us8*)&Wlo[(size_t)n * K + k1 + skg * 8];
      }
    }

    us8 bh[4], bl[4];
#pragma unroll
    for (int nf = 0; nf < 4; nf++) {
      int n = w * 64 + nf * 16 + lr;
      bh[nf] = *(us8*)&Bs[0][(kg * 256 + n) * 8];
      bl[nf] = *(us8*)&Bs[1][(kg * 256 + n) * 8];
    }
#pragma unroll
    for (int m = 0; m < 4; m++) {
      int row = m * 16 + lr;
      us8 ah = *(us8*)&As[(kg * 64 + row) * 8];
#pragma unroll
      for (int nf = 0; nf < 4; nf++) {
        acc[m][nf] = MFMA16(ah, bh[nf], acc[m][nf]);
        acc[m][nf] = MFMA16(ah, bl[nf], acc[m][nf]);
      }
    }
  }

  // epilogue: store h (fp16) + reduce als/ald (scaled by log2e) for head w.
  // C layout: col = nf*16 + lr, row = m*16 + kg*4 + r
  int head = w;
  float asv[4], adv[4];
#pragma unroll
  for (int nf = 0; nf < 4; nf++) {
    asv[nf] = a_s[head * HID + nf * 16 + lr];
    adv[nf] = a_d[head * HID + nf * 16 + lr];
  }
#pragma unroll
  for (int m = 0; m < 4; m++) {
#pragma unroll
    for (int r = 0; r < 4; r++) {
      int grow = mt * 64 + m * 16 + kg * 4 + r;
      float ps = 0.f, pd = 0.f;
#pragma unroll
      for (int nf = 0; nf < 4; nf++) {
        float v = acc[m][nf][r];
        ps += v * asv[nf];
        pd += v * adv[nf];
        if (grow < N_NODES)
          hbuf16[(size_t)grow * HC + head * 64 + nf * 16 + lr] = (_Float16)v;
      }
#pragma unroll
      for (int msk = 1; msk < 16; msk <<= 1) {
        ps += __shfl_xor(ps, msk, 64);
        pd += __shfl_xor(pd, msk, 64);
      }
      if (lr == 0 && grow < N_NODES) {
        als[grow * HEADS + head] = ps * L2E;
        ald[grow * HEADS + head] = pd * L2E;
      }
    }
  }
}

// ---------------- dual-stream per-destination softmax + aggregate (R7 keeper) ----------------

template <int MODE>
__global__ __launch_bounds__(256) void agg_kernel(
    const _Float16* __restrict__ hbuf16, const float* __restrict__ alsE,
    const float* __restrict__ aldE, const int* __restrict__ rowptr,
    const int* __restrict__ csr_src, const float* __restrict__ bias,
    unsigned short* __restrict__ ohi, float* __restrict__ pooled,
    const int* __restrict__ batch) {
  int wave = threadIdx.x >> 6;
  int lane = threadIdx.x & 63;
  int v0 = blockIdx.x * 8 + wave * 2;
  int v1 = v0 + 1;
  int head = lane >> 4;
  float ald0 = aldE[(unsigned)v0 * HEADS + head];
  float ald1 = aldE[(unsigned)v1 * HEADS + head];
  int beg0 = rowptr[v0], n0 = rowptr[v0 + 1] - beg0;
  int beg1 = rowptr[v1], n1 = rowptr[v1 + 1] - beg1;
  int n = max(n0, n1);

  float den0 = 0.f, den1 = 0.f;
  f32x4 acc0 = {0.f, 0.f, 0.f, 0.f};
  f32x4 acc1 = {0.f, 0.f, 0.f, 0.f};
  const _Float16* hp = hbuf16 + (lane << 2);
#pragma unroll 2
  for (int i = 0; i < n; i++) {
    int s0 = csr_src[beg0 + min(i, n0 - 1)];
    int s1 = csr_src[beg1 + min(i, n1 - 1)];
    float a0 = alsE[(unsigned)s0 * HEADS + head] + ald0;
    float a1 = alsE[(unsigned)s1 * HEADS + head] + ald1;
    a0 = fmaxf(a0, SLOPE * a0);
    a1 = fmaxf(a1, SLOPE * a1);
    float ex0 = (i < n0) ? __builtin_amdgcn_exp2f(a0) : 0.f;
    float ex1 = (i < n1) ? __builtin_amdgcn_exp2f(a1) : 0.f;
    h16x4 h0 = *(const h16x4*)(hp + ((unsigned)s0 << 8));
    h16x4 h1 = *(const h16x4*)(hp + ((unsigned)s1 << 8));
    den0 += ex0; den1 += ex1;
    acc0[0] += (float)h0[0] * ex0; acc0[1] += (float)h0[1] * ex0;
    acc0[2] += (float)h0[2] * ex0; acc0[3] += (float)h0[3] * ex0;
    acc1[0] += (float)h1[0] * ex1; acc1[1] += (float)h1[1] * ex1;
    acc1[2] += (float)h1[2] * ex1; acc1[3] += (float)h1[3] * ex1;
  }
  float inv0 = 1.0f / (den0 + 1e-16f);
  float inv1 = 1.0f / (den1 + 1e-16f);
  float4 bv = *(const float4*)&bias[lane * 4];
  float o0[4], o1[4];
  o0[0] = acc0[0] * inv0 + bv.x; o0[1] = acc0[1] * inv0 + bv.y;
  o0[2] = acc0[2] * inv0 + bv.z; o0[3] = acc0[3] * inv0 + bv.w;
  o1[0] = acc1[0] * inv1 + bv.x; o1[1] = acc1[1] * inv1 + bv.y;
  o1[2] = acc1[2] * inv1 + bv.z; o1[3] = acc1[3] * inv1 + bv.w;

  if (MODE == 0) {
    us4 h0, h1;
#pragma unroll
    for (int j = 0; j < 4; j++) {
      h0[j] = f2bf_rne(fmaxf(o0[j], 0.f));
      h1[j] = f2bf_rne(fmaxf(o1[j], 0.f));
    }
    *(us4*)&ohi[(size_t)v0 * HC + lane * 4] = h0;
    *(us4*)&ohi[(size_t)v1 * HC + lane * 4] = h1;
  } else {
    __shared__ float pacc[8][HC];
    __shared__ int pg[8];
    f32x4 ov0 = {o0[0], o0[1], o0[2], o0[3]};
    f32x4 ov1 = {o1[0], o1[1], o1[2], o1[3]};
    *(f32x4*)&pacc[wave * 2][lane * 4] = ov0;
    *(f32x4*)&pacc[wave * 2 + 1][lane * 4] = ov1;
    if (lane == 0) {
      pg[wave * 2] = batch[v0];
      pg[wave * 2 + 1] = batch[v1];
    }
    __syncthreads();
    int c = threadIdx.x;
    float s = pacc[0][c];
    int gcur = pg[0];
#pragma unroll
    for (int wv = 1; wv < 8; wv++) {
      if (pg[wv] != gcur) {
        atomicAdd(&pooled[gcur * HC + c], s);
        s = 0.f;
        gcur = pg[wv];
      }
      s += pacc[wv][c];
    }
    atomicAdd(&pooled[gcur * HC + c], s);
  }
}

// ---------------- MLP head (fused mean-divide) ----------------

__global__ __launch_bounds__(64) void mlp_kernel(const float* __restrict__ pooled_sum,
                                                 const int* __restrict__ batch,
                                                 const float* __restrict__ w1,
                                                 const float* __restrict__ b1,
                                                 const float* __restrict__ w2,
                                                 const float* __restrict__ b2,
                                                 float* __restrict__ out) {
  int g = blockIdx.x;
  int j = threadIdx.x;
  int lo = 0, hi = N_NODES;
  while (lo < hi) { int mid = (lo + hi) >> 1; if (batch[mid] < g) lo = mid + 1; else hi = mid; }
  int start = lo;
  hi = N_NODES;
  while (lo < hi) { int mid = (lo + hi) >> 1; if (batch[mid] < g + 1) lo = mid + 1; else hi = mid; }
  float invc = 1.0f / fmaxf((float)(lo - start), 1.0f);
  __shared__ float z[HID];
  float acc = 0.f;
  for (int k = 0; k < HC; k++) acc += pooled_sum[g * HC + k] * w1[j * HC + k];
  z[j] = fmaxf(acc * invc + b1[j], 0.f);
  __syncthreads();
  if (j < NC) {
    float o = b2[j];
    for (int k = 0; k < HID; k++) o += z[k] * w2[j * HID + k];
    out[g * NC + j] = o;
  }
}

// ---------------- launch ----------------

extern "C" void kernel_launch(void* const* d_in, const int* in_sizes, int n_in,
                              void* d_out, int out_size, void* d_ws, size_t ws_size,
                              hipStream_t stream) {
  const float* x    = (const float*)d_in[0];
  const int*   ei   = (const int*)d_in[1];
  const int*   batch= (const int*)d_in[2];
  const float* W1   = (const float*)d_in[3];
  const float* as1  = (const float*)d_in[4];
  const float* ad1  = (const float*)d_in[5];
  const float* b1   = (const float*)d_in[6];
  const float* W2   = (const float*)d_in[7];
  const float* as2  = (const float*)d_in[8];
  const float* ad2  = (const float*)d_in[9];
  const float* b2   = (const float*)d_in[10];
  const float* W3   = (const float*)d_in[11];
  const float* as3  = (const float*)d_in[12];
  const float* ad3  = (const float*)d_in[13];
  const float* b3   = (const float*)d_in[14];
  const float* fc1w = (const float*)d_in[15];
  const float* fc1b = (const float*)d_in[16];
  const float* fc2w = (const float*)d_in[17];
  const float* fc2b = (const float*)d_in[18];
  float* out = (float*)d_out;

  char* ws = (char*)d_ws;
  size_t off = 0;
  _Float16* hbuf16 = (_Float16*)(ws + off); off += (size_t)N_NODES * HC * 2;
  unsigned short* ahi = (unsigned short*)(ws + off); off += (size_t)N_NODES * HC * 2;
  unsigned short* xhi = (unsigned short*)(ws + off); off += (size_t)N_NODES * IN_F * 2;
  unsigned short* w1h = (unsigned short*)(ws + off); off += (size_t)HC * IN_F * 2;
  unsigned short* w1l = (unsigned short*)(ws + off); off += (size_t)HC * IN_F * 2;
  unsigned short* w2h = (unsigned short*)(ws + off); off += (size_t)HC * HC * 2;
  unsigned short* w2l = (unsigned short*)(ws + off); off += (size_t)HC * HC * 2;
  unsigned short* w3h = (unsigned short*)(ws + off); off += (size_t)HC * HC * 2;
  unsigned short* w3l = (unsigned short*)(ws + off); off += (size_t)HC * HC * 2;
  float* als    = (float*)(ws + off); off += (size_t)N_NODES * HEADS * 4;
  float* ald    = (float*)(ws + off); off += (size_t)N_NODES * HEADS * 4;
  float* pooled = (float*)(ws + off); off += (size_t)G_GRAPHS * HC * 4;
  int*   cnt    = (int*)(ws + off);   off += (size_t)N_NODES * 4;
  int*   cursor = (int*)(ws + off);   off += (size_t)N_NODES * 4;
  int*   csrsrc = (int*)(ws + off);   off += (size_t)ET * 4;
  int*   rowptr = (int*)(ws + off);   off += (size_t)(N_NODES + 1) * 4;
  int*   partial= (int*)(ws + off);   off += 256 * 4;

  // --- fused splits (independent of CSR) ---
  split_all_kernel<<<(QTOT + 255) / 256, 256, 0, stream>>>(
      x, W1, W2, W3, xhi, w1h, w1l, w2h, w2l, w3h, w3l);

  // --- CSR build ---
  hipMemsetAsync(cnt, 0, (size_t)N_NODES * 4, stream);
  hipMemsetAsync(pooled, 0, (size_t)G_GRAPHS * HC * 4, stream);
  count_kernel<<<(ET + 255) / 256, 256, 0, stream>>>(ei, cnt);
  scan1_kernel<<<SCAN_BLOCKS, 256, 0, stream>>>(cnt, cursor, partial);
  scan2_kernel<<<1, 256, 0, stream>>>(partial);
  scan3_kernel<<<SCAN_BLOCKS, 256, 0, stream>>>(cnt, cursor, partial, rowptr, cursor);
  scatter_kernel<<<(ET + 255) / 256, 256, 0, stream>>>(ei, cursor, csrsrc);

  dim3 gemm_grid((N_NODES + 63) / 64);
  int agg_grid = N_NODES / 8;  // exact: 50000 % 8 == 0

  // --- layer 1 ---
  mfma_gemm_kernel<IN_F><<<gemm_grid, 256, 0, stream>>>(xhi, w1h, w1l, as1, ad1, hbuf16, als, ald);
  agg_kernel<0><<<agg_grid, 256, 0, stream>>>(hbuf16, als, ald, rowptr, csrsrc, b1, ahi, nullptr, nullptr);
  // --- layer 2 ---
  mfma_gemm_kernel<HC><<<gemm_grid, 256, 0, stream>>>(ahi, w2h, w2l, as2, ad2, hbuf16, als, ald);
  agg_kernel<0><<<agg_grid, 256, 0, stream>>>(hbuf16, als, ald, rowptr, csrsrc, b2, ahi, nullptr, nullptr);
  // --- layer 3 (fused mean-pool accumulate) ---
  mfma_gemm_kernel<HC><<<gemm_grid, 256, 0, stream>>>(ahi, w3h, w3l, as3, ad3, hbuf16, als, ald);
  agg_kernel<1><<<agg_grid, 256, 0, stream>>>(hbuf16, als, ald, rowptr, csrsrc, b3, nullptr, pooled, batch);

  // --- MLP (with fused mean divide) ---
  mlp_kernel<<<G_GRAPHS, 64, 0, stream>>>(pooled, batch, fc1w, fc1b, fc2w, fc2b, out);
}